// Round 14
// baseline (461.867 us; speedup 1.0000x reference)
//
#include <hip/hip_runtime.h>
#include <hip/hip_bf16.h>

#define N_NODES 20000
#define N_EDGES 320000
#define HD 512

typedef __attribute__((ext_vector_type(8))) short bf16x8;
typedef __attribute__((ext_vector_type(4))) float f32x4;

// ---------- bf16 helpers ----------
__device__ inline ushort f2bf(float f) {
    uint u = __float_as_uint(f);
    uint r = (u + 0x7fffu + ((u >> 16) & 1u)) >> 16;
    return (ushort)r;
}
__device__ inline uint pack2(float a, float b) {
    return (uint)f2bf(a) | ((uint)f2bf(b) << 16);
}
__device__ inline float bflo(uint u) { return __uint_as_float(u << 16); }
__device__ inline float bfhi(uint u) { return __uint_as_float(u & 0xffff0000u); }

__device__ __forceinline__ void async_load16(const void* g, void* l) {
    __builtin_amdgcn_global_load_lds(
        (const __attribute__((address_space(1))) uint*)g,
        (__attribute__((address_space(3))) uint*)l,
        16, 0, 0);
}

// ---------- gemm tile: 128x128, global_load_lds, XOR swizzle (proven) -------
__device__ __forceinline__ void gemm_tile(const ushort* __restrict__ A,
                                          const ushort* __restrict__ Bt,
                                          ushort* __restrict__ C,
                                          int tile, char* smem) {
    short* As = (short*)smem;
    short* Bs = (short*)(smem + 128 * 32 * 2);
    const int tid = threadIdx.x;
    const int lane = tid & 63;
    const int wave = tid >> 6;
    const int l15 = lane & 15;
    const int q = lane >> 4;
    const int wrow = wave >> 1, wcol = wave & 1;
    const int row0 = (tile >> 2) * 128;
    const int col0 = (tile & 3) * 128;

    const int srow = lane >> 2;
    const int kc   = (lane & 3) ^ ((lane >> 3) & 3);
    const int sl   = (l15 >> 1) & 3;

    f32x4 acc[4][4] = {};

    for (int k0 = 0; k0 < HD; k0 += 32) {
        #pragma unroll
        for (int l = 0; l < 2; ++l) {
            const int rbase = wave * 32 + l * 16;
            const ushort* ga = &A [(size_t)(row0 + rbase + srow) * HD + k0 + kc * 8];
            const ushort* gb = &Bt[(size_t)(col0 + rbase + srow) * HD + k0 + kc * 8];
            async_load16(ga, &As[rbase * 32]);
            async_load16(gb, &Bs[rbase * 32]);
        }
        __syncthreads();
        bf16x8 aF[4], bF[4];
        #pragma unroll
        for (int i = 0; i < 4; ++i)
            aF[i] = *(bf16x8*)&As[(wrow * 64 + i * 16 + l15) * 32 + (q ^ sl) * 8];
        #pragma unroll
        for (int j = 0; j < 4; ++j)
            bF[j] = *(bf16x8*)&Bs[(wcol * 64 + j * 16 + l15) * 32 + (q ^ sl) * 8];
        #pragma unroll
        for (int i = 0; i < 4; ++i)
            #pragma unroll
            for (int j = 0; j < 4; ++j)
                acc[i][j] = __builtin_amdgcn_mfma_f32_16x16x32_bf16(aF[i], bF[j], acc[i][j], 0, 0, 0);
        __syncthreads();
    }
    #pragma unroll
    for (int i = 0; i < 4; ++i) {
        #pragma unroll
        for (int r = 0; r < 4; ++r) {
            int gr = row0 + wrow * 64 + i * 16 + q * 4 + r;
            if (gr < N_NODES) {
                #pragma unroll
                for (int j = 0; j < 4; ++j) {
                    int gc = col0 + wcol * 64 + j * 16 + l15;
                    C[(size_t)gr * HD + gc] = f2bf(acc[i][j][r]);
                }
            }
        }
    }
}

// ---------- pool partial (proven) ----------
__device__ __forceinline__ void pool_part(const ushort* __restrict__ h,
                                          float* __restrict__ pmax,
                                          float* __restrict__ psum,
                                          int pb, char* smem) {
    float* lmx = (float*)smem;           // 2048 floats
    float* lsm = lmx + 2048;             // 2048 floats
    const int tid = threadIdx.x;
    const int wave = tid >> 6, lane = tid & 63;
    const uint4* h4 = (const uint4*)h;
    float m[8] = {}, sm[8] = {};
    for (int r = pb * 4 + wave; r < N_NODES; r += 1024) {
        uint4 v = h4[(size_t)r * 64 + lane];
        m[0] = fmaxf(m[0], bflo(v.x)); sm[0] += bflo(v.x);
        m[1] = fmaxf(m[1], bfhi(v.x)); sm[1] += bfhi(v.x);
        m[2] = fmaxf(m[2], bflo(v.y)); sm[2] += bflo(v.y);
        m[3] = fmaxf(m[3], bfhi(v.y)); sm[3] += bfhi(v.y);
        m[4] = fmaxf(m[4], bflo(v.z)); sm[4] += bflo(v.z);
        m[5] = fmaxf(m[5], bfhi(v.z)); sm[5] += bfhi(v.z);
        m[6] = fmaxf(m[6], bflo(v.w)); sm[6] += bflo(v.w);
        m[7] = fmaxf(m[7], bfhi(v.w)); sm[7] += bfhi(v.w);
    }
    #pragma unroll
    for (int i = 0; i < 8; ++i) {
        lmx[wave * 512 + lane * 8 + i] = m[i];
        lsm[wave * 512 + lane * 8 + i] = sm[i];
    }
    __syncthreads();
    #pragma unroll
    for (int cc = 0; cc < 2; ++cc) {
        int ch = tid * 2 + cc;
        float mx = fmaxf(fmaxf(lmx[ch], lmx[512 + ch]),
                         fmaxf(lmx[1024 + ch], lmx[1536 + ch]));
        float sv = (lsm[ch] + lsm[512 + ch]) + (lsm[1024 + ch] + lsm[1536 + ch]);
        atomicMax((int*)&pmax[ch], __float_as_int(mx));   // values >= 0
        atomicAdd(&psum[ch], sv);
    }
}

// ---------- prep: cvt x | wt transpose | zero deg/pmax/psum ----------
#define NB_CVT 5000
#define NB_WT  192
#define NB_ZD  79
__global__ __launch_bounds__(256) void prep_k(const float* __restrict__ x,
                                              ushort* __restrict__ xb,
                                              const float* __restrict__ W1,
                                              const float* __restrict__ W2,
                                              const float* __restrict__ W3,
                                              ushort* __restrict__ T1,
                                              ushort* __restrict__ T2,
                                              ushort* __restrict__ T3,
                                              int* __restrict__ deg,
                                              float* __restrict__ pmax,
                                              float* __restrict__ psum) {
    __shared__ float t[64][65];
    const int b = blockIdx.x;
    const int tid = threadIdx.x;
    if (b < NB_CVT) {
        int c = b * 256 + tid;
        const float4* p = (const float4*)x + (size_t)c * 2;
        float4 a = p[0], q = p[1];
        uint4 o;
        o.x = pack2(a.x, a.y); o.y = pack2(a.z, a.w);
        o.z = pack2(q.x, q.y); o.w = pack2(q.z, q.w);
        ((uint4*)xb)[c] = o;
    } else if (b < NB_CVT + NB_WT) {
        int idx = b - NB_CVT;
        int layer = idx >> 6, rem = idx & 63;
        const float* W = (layer == 0) ? W1 : (layer == 1) ? W2 : W3;
        ushort* T      = (layer == 0) ? T1 : (layer == 1) ? T2 : T3;
        int kb = (rem >> 3) * 64, nb = (rem & 7) * 64;
        int c = tid & 63, r4 = tid >> 6;
        #pragma unroll
        for (int l = 0; l < 16; ++l) {
            int r = l * 4 + r4;
            t[r][c] = W[(size_t)(kb + r) * HD + nb + c];
        }
        __syncthreads();
        #pragma unroll
        for (int l = 0; l < 16; ++l) {
            int r = l * 4 + r4;
            T[(size_t)(nb + r) * HD + kb + c] = f2bf(t[c][r]);
        }
    } else if (b < NB_CVT + NB_WT + NB_ZD) {
        int i = (b - NB_CVT - NB_WT) * 256 + tid;
        if (i < N_NODES) deg[i] = 0;
    } else if (b < NB_CVT + NB_WT + NB_ZD + 6) {
        int i = (b - NB_CVT - NB_WT - NB_ZD) * 256 + tid;
        pmax[i] = 0.f;
    } else {
        int i = (b - NB_CVT - NB_WT - NB_ZD - 6) * 256 + tid;
        psum[i] = 0.f;
    }
}

// ---------- fused1: gemm layer1 (0..627) || hist (628..1877) ----------
__global__ __launch_bounds__(256) void fused1_k(const ushort* __restrict__ xb,
                                                const ushort* __restrict__ wt1,
                                                ushort* __restrict__ s,
                                                const int* __restrict__ rows,
                                                int* __restrict__ deg) {
    __shared__ __align__(16) char smem[16384];
    const int b = blockIdx.x;
    if (b < 628) {
        gemm_tile(xb, wt1, s, b, smem);
    } else {
        int e = (b - 628) * 256 + threadIdx.x;   // 1250*256 == N_EDGES exactly
        atomicAdd(&deg[rows[e]], 1);
    }
}

// ---------- scan: one workgroup, 16 waves, shuffle (proven ~4 µs) ----------
__global__ __launch_bounds__(1024) void scan_k(const int* __restrict__ deg,
                                               int* __restrict__ rowstart,
                                               int* __restrict__ cursor) {
    __shared__ int wsum[16];
    const int tid = threadIdx.x;
    const int lane = tid & 63, wv = tid >> 6;
    int carry = 0;
    for (int base = 0; base < N_NODES; base += 1024) {
        int i = base + tid;
        int v = (i < N_NODES) ? deg[i] : 0;
        int incl = v;
        #pragma unroll
        for (int off = 1; off < 64; off <<= 1) {
            int t = __shfl_up(incl, off, 64);
            if (lane >= off) incl += t;
        }
        if (lane == 63) wsum[wv] = incl;
        __syncthreads();
        int woff = 0, tot = 0;
        #pragma unroll
        for (int w = 0; w < 16; ++w) {
            int sv = wsum[w];
            if (w < wv) woff += sv;
            tot += sv;
        }
        if (i < N_NODES) {
            int ex = carry + woff + incl - v;
            rowstart[i] = ex;
            cursor[i]   = ex;
        }
        carry += tot;
        __syncthreads();
    }
    if (tid == 0) rowstart[N_NODES] = carry;
}

// ---------- fill CSR ----------
__global__ void fill_k(const int* __restrict__ rows, const int* __restrict__ cols,
                       const float* __restrict__ vals, int* __restrict__ cursor,
                       int* __restrict__ csr_col, float* __restrict__ csr_val) {
    int e = blockIdx.x * blockDim.x + threadIdx.x;
    if (e < N_EDGES) {
        int p = atomicAdd(&cursor[rows[e]], 1);
        csr_col[p] = cols[e];
        csr_val[p] = vals[e];
    }
}

// ---------- aggregate, channel-chunked, 8 edges/wave with uint4 loads -------
// grid (5000, 8): chunk cz = 64 channels = 128 B/row -> working set 2.56 MB/XCD L2.
// Wave: 8 groups of 8 lanes; group g handles edges beg+g, beg+g+8, ...
// Lane i of group g reads s4[col*64 + cz*8 + i] (16 B). Cross-group combine
// via 3x shfl_xor. Group 0 writes the 128 B output slice.
__device__ inline void fma8(float* acc, uint4 v, float w) {
    acc[0] += w * bflo(v.x); acc[1] += w * bfhi(v.x);
    acc[2] += w * bflo(v.y); acc[3] += w * bfhi(v.y);
    acc[4] += w * bflo(v.z); acc[5] += w * bfhi(v.z);
    acc[6] += w * bflo(v.w); acc[7] += w * bfhi(v.w);
}

__global__ __launch_bounds__(256) void agg_k(const ushort* __restrict__ s,
                                             const int* __restrict__ rowstart,
                                             const int* __restrict__ csr_col,
                                             const float* __restrict__ csr_val,
                                             const float* __restrict__ bias,
                                             ushort* __restrict__ hout) {
    const int wave = threadIdx.x >> 6, lane = threadIdx.x & 63;
    const int g = lane >> 3, i = lane & 7;
    const int r = blockIdx.x * 4 + wave;
    const int cz = blockIdx.y;
    const uint4* s4 = (const uint4*)s;
    const int coff = cz * 8 + i;            // uint4 index within row (64/row)

    const int beg = rowstart[r], end = rowstart[r + 1];
    float acc[8] = {};
    int j = beg + g;
    for (; j + 8 < end; j += 16) {          // 2 edges per group in flight
        int   c0 = csr_col[j],   c1 = csr_col[j + 8];
        float w0 = csr_val[j],   w1 = csr_val[j + 8];
        uint4 v0 = s4[(size_t)c0 * 64 + coff];
        uint4 v1 = s4[(size_t)c1 * 64 + coff];
        fma8(acc, v0, w0);
        fma8(acc, v1, w1);
    }
    if (j < end) {
        int   c0 = csr_col[j];
        float w0 = csr_val[j];
        uint4 v0 = s4[(size_t)c0 * 64 + coff];
        fma8(acc, v0, w0);
    }
    // combine the 8 groups (same channels, different edges)
    #pragma unroll
    for (int k = 0; k < 8; ++k) {
        acc[k] += __shfl_xor(acc[k], 8, 64);
        acc[k] += __shfl_xor(acc[k], 16, 64);
        acc[k] += __shfl_xor(acc[k], 32, 64);
    }
    if (g == 0) {
        float4 b0 = ((const float4*)bias)[cz * 16 + i * 2];
        float4 b1 = ((const float4*)bias)[cz * 16 + i * 2 + 1];
        float o[8];
        o[0] = fmaxf(acc[0] + b0.x, 0.f); o[1] = fmaxf(acc[1] + b0.y, 0.f);
        o[2] = fmaxf(acc[2] + b0.z, 0.f); o[3] = fmaxf(acc[3] + b0.w, 0.f);
        o[4] = fmaxf(acc[4] + b1.x, 0.f); o[5] = fmaxf(acc[5] + b1.y, 0.f);
        o[6] = fmaxf(acc[6] + b1.z, 0.f); o[7] = fmaxf(acc[7] + b1.w, 0.f);
        uint4 ov;
        ov.x = pack2(o[0], o[1]); ov.y = pack2(o[2], o[3]);
        ov.z = pack2(o[4], o[5]); ov.w = pack2(o[6], o[7]);
        ((uint4*)hout)[(size_t)r * 64 + coff] = ov;
    }
}

// ---------- fused gemm || pool (both read-only on h; validated R12/R13) -----
__global__ __launch_bounds__(256) void fusedgp_k(const ushort* __restrict__ h,
                                                 const ushort* __restrict__ wt,
                                                 ushort* __restrict__ s,
                                                 float* __restrict__ pmax,
                                                 float* __restrict__ psum) {
    __shared__ __align__(16) char smem[16384];
    const int b = blockIdx.x;
    if (b < 628) gemm_tile(h, wt, s, b, smem);
    else         pool_part(h, pmax, psum, b - 628, smem);
}

// ---------- standalone pool (layer 3) ----------
__global__ __launch_bounds__(256) void pool_k(const ushort* __restrict__ h,
                                              float* __restrict__ pmax,
                                              float* __restrict__ psum) {
    __shared__ __align__(16) char smem[16384];
    pool_part(h, pmax, psum, blockIdx.x, smem);
}

// ---------- head MLP + log_softmax (1024 threads, split-k; proven) ----------
__global__ __launch_bounds__(1024) void mlp_k(const float* __restrict__ pool_max,
                                              const float* __restrict__ pool_sum,
                                              const float* __restrict__ l1W,
                                              const float* __restrict__ l1b,
                                              const float* __restrict__ l2W,
                                              const float* __restrict__ l2b,
                                              const float* __restrict__ l3W,
                                              const float* __restrict__ l3b,
                                              float* __restrict__ out) {
    __shared__ float g[1024];
    __shared__ float part[1024];
    __shared__ float a1[128];
    __shared__ float a2[64];
    __shared__ float a3[10];
    const int tid = threadIdx.x;
    if (tid < 512) {
        g[tid]       = pool_max[tid] + pool_max[512 + tid] + pool_max[1024 + tid];
        g[512 + tid] = (pool_sum[tid] + pool_sum[512 + tid] + pool_sum[1024 + tid]) *
                       (1.0f / N_NODES);
    }
    __syncthreads();
    {
        int ch = tid & 127, sl = tid >> 7;
        float acc = (sl == 0) ? l1b[ch] : 0.f;
        int k0 = sl * 128;
        #pragma unroll 4
        for (int k = k0; k < k0 + 128; ++k) acc += g[k] * l1W[k * 128 + ch];
        part[tid] = acc;
    }
    __syncthreads();
    if (tid < 128) {
        float a = part[tid];
        #pragma unroll
        for (int ss = 1; ss < 8; ++ss) a += part[tid + ss * 128];
        a1[tid] = fmaxf(a, 0.f);
    }
    __syncthreads();
    if (tid < 512) {
        int ch = tid & 63, sl = tid >> 6;
        float acc = (sl == 0) ? l2b[ch] : 0.f;
        int k0 = sl * 16;
        #pragma unroll
        for (int k = k0; k < k0 + 16; ++k) acc += a1[k] * l2W[k * 64 + ch];
        part[tid] = acc;
    }
    __syncthreads();
    if (tid < 64) {
        float a = part[tid];
        #pragma unroll
        for (int ss = 1; ss < 8; ++ss) a += part[tid + ss * 64];
        a2[tid] = fmaxf(a, 0.f);
    }
    __syncthreads();
    if (tid < 10) {
        float acc = l3b[tid];
        for (int k = 0; k < 64; ++k) acc += a2[k] * l3W[k * 10 + tid];
        a3[tid] = acc;
    }
    __syncthreads();
    if (tid == 0) {
        float m = a3[0];
        for (int j = 1; j < 10; ++j) m = fmaxf(m, a3[j]);
        float ssum = 0.f;
        for (int j = 0; j < 10; ++j) ssum += expf(a3[j] - m);
        float lse = m + logf(ssum);
        for (int j = 0; j < 10; ++j) out[j] = a3[j] - lse;
    }
}

extern "C" void kernel_launch(void* const* d_in, const int* in_sizes, int n_in,
                              void* d_out, int out_size, void* d_ws, size_t ws_size,
                              hipStream_t stream) {
    const float* x    = (const float*)d_in[0];
    const int*   rows = (const int*)  d_in[1];
    const int*   cols = (const int*)  d_in[2];
    const float* vals = (const float*)d_in[3];
    const float* W1   = (const float*)d_in[4];
    const float* b1   = (const float*)d_in[5];
    const float* W2   = (const float*)d_in[6];
    const float* b2   = (const float*)d_in[7];
    const float* W3   = (const float*)d_in[8];
    const float* b3   = (const float*)d_in[9];
    const float* l1W  = (const float*)d_in[10];
    const float* l1b  = (const float*)d_in[11];
    const float* l2W  = (const float*)d_in[12];
    const float* l2b  = (const float*)d_in[13];
    const float* l3W  = (const float*)d_in[14];
    const float* l3b  = (const float*)d_in[15];
    float* out = (float*)d_out;

    char* ws = (char*)d_ws;
    size_t off = 0;
    auto alloc = [&](size_t bytes) {
        void* p = ws + off;
        off += (bytes + 255) & ~(size_t)255;
        return p;
    };
    ushort* xb       = (ushort*)alloc((size_t)N_NODES * HD * 2);
    ushort* s        = (ushort*)alloc((size_t)N_NODES * HD * 2);
    ushort* hb       = (ushort*)alloc((size_t)N_NODES * HD * 2);
    ushort* wt1      = (ushort*)alloc((size_t)HD * HD * 2);
    ushort* wt2      = (ushort*)alloc((size_t)HD * HD * 2);
    ushort* wt3      = (ushort*)alloc((size_t)HD * HD * 2);
    int*    deg      = (int*)   alloc((size_t)N_NODES * 4);
    float*  pmax     = (float*) alloc((size_t)3 * 512 * 4);
    float*  psum     = (float*) alloc((size_t)3 * 512 * 4);
    int*    rowstart = (int*)   alloc((size_t)(N_NODES + 1) * 4);
    int*    cursor   = (int*)   alloc((size_t)N_NODES * 4);
    int*    csr_col  = (int*)   alloc((size_t)N_EDGES * 4);
    float*  csr_val  = (float*) alloc((size_t)N_EDGES * 4);
    (void)ws_size; (void)in_sizes; (void)n_in; (void)out_size;

    // 1: prep (cvt + wt + zero deg/pmax/psum)
    prep_k<<<NB_CVT + NB_WT + NB_ZD + 12, 256, 0, stream>>>(
        x, xb, W1, W2, W3, wt1, wt2, wt3, deg, pmax, psum);
    // 2: gemm1 || hist
    fused1_k<<<628 + 1250, 256, 0, stream>>>(xb, wt1, s, rows, deg);
    // 3: scan
    scan_k<<<1, 1024, 0, stream>>>(deg, rowstart, cursor);
    // 4: fill CSR
    fill_k<<<(N_EDGES + 255) / 256, 256, 0, stream>>>(rows, cols, vals, cursor,
                                                      csr_col, csr_val);
    dim3 agrid(N_NODES / 4, 8);
    // 5: agg1
    agg_k<<<agrid, 256, 0, stream>>>(s, rowstart, csr_col, csr_val, b1, hb);
    // 6: gemm2 || pool1
    fusedgp_k<<<628 + 256, 256, 0, stream>>>(hb, wt2, s, pmax, psum);
    // 7: agg2
    agg_k<<<agrid, 256, 0, stream>>>(s, rowstart, csr_col, csr_val, b2, hb);
    // 8: gemm3 || pool2
    fusedgp_k<<<628 + 256, 256, 0, stream>>>(hb, wt3, s, pmax + 512, psum + 512);
    // 9: agg3
    agg_k<<<agrid, 256, 0, stream>>>(s, rowstart, csr_col, csr_val, b3, hb);
    // 10: pool3
    pool_k<<<256, 256, 0, stream>>>(hb, pmax + 1024, psum + 1024);
    // 11: mlp head
    mlp_k<<<1, 1024, 0, stream>>>(pmax, psum, l1W, l1b, l2W, l2b, l3W, l3b, out);
}

// Round 15
// 399.178 us; speedup vs baseline: 1.1570x; 1.1570x over previous
//
#include <hip/hip_runtime.h>
#include <hip/hip_bf16.h>

#define N_NODES 20000
#define N_EDGES 320000
#define HD 512

typedef __attribute__((ext_vector_type(8))) short bf16x8;
typedef __attribute__((ext_vector_type(4))) float f32x4;

// ---------- bf16 helpers ----------
__device__ inline ushort f2bf(float f) {
    uint u = __float_as_uint(f);
    uint r = (u + 0x7fffu + ((u >> 16) & 1u)) >> 16;
    return (ushort)r;
}
__device__ inline uint pack2(float a, float b) {
    return (uint)f2bf(a) | ((uint)f2bf(b) << 16);
}
__device__ inline float bflo(uint u) { return __uint_as_float(u << 16); }
__device__ inline float bfhi(uint u) { return __uint_as_float(u & 0xffff0000u); }

__device__ __forceinline__ void async_load16(const void* g, void* l) {
    __builtin_amdgcn_global_load_lds(
        (const __attribute__((address_space(1))) uint*)g,
        (__attribute__((address_space(3))) uint*)l,
        16, 0, 0);
}

// ---------- gemm tile: 128x128, global_load_lds, XOR swizzle (proven) -------
__device__ __forceinline__ void gemm_tile(const ushort* __restrict__ A,
                                          const ushort* __restrict__ Bt,
                                          ushort* __restrict__ C,
                                          int tile, char* smem) {
    short* As = (short*)smem;
    short* Bs = (short*)(smem + 128 * 32 * 2);
    const int tid = threadIdx.x;
    const int lane = tid & 63;
    const int wave = tid >> 6;
    const int l15 = lane & 15;
    const int q = lane >> 4;
    const int wrow = wave >> 1, wcol = wave & 1;
    const int row0 = (tile >> 2) * 128;
    const int col0 = (tile & 3) * 128;

    const int srow = lane >> 2;
    const int kc   = (lane & 3) ^ ((lane >> 3) & 3);
    const int sl   = (l15 >> 1) & 3;

    f32x4 acc[4][4] = {};

    for (int k0 = 0; k0 < HD; k0 += 32) {
        #pragma unroll
        for (int l = 0; l < 2; ++l) {
            const int rbase = wave * 32 + l * 16;
            const ushort* ga = &A [(size_t)(row0 + rbase + srow) * HD + k0 + kc * 8];
            const ushort* gb = &Bt[(size_t)(col0 + rbase + srow) * HD + k0 + kc * 8];
            async_load16(ga, &As[rbase * 32]);
            async_load16(gb, &Bs[rbase * 32]);
        }
        __syncthreads();
        bf16x8 aF[4], bF[4];
        #pragma unroll
        for (int i = 0; i < 4; ++i)
            aF[i] = *(bf16x8*)&As[(wrow * 64 + i * 16 + l15) * 32 + (q ^ sl) * 8];
        #pragma unroll
        for (int j = 0; j < 4; ++j)
            bF[j] = *(bf16x8*)&Bs[(wcol * 64 + j * 16 + l15) * 32 + (q ^ sl) * 8];
        #pragma unroll
        for (int i = 0; i < 4; ++i)
            #pragma unroll
            for (int j = 0; j < 4; ++j)
                acc[i][j] = __builtin_amdgcn_mfma_f32_16x16x32_bf16(aF[i], bF[j], acc[i][j], 0, 0, 0);
        __syncthreads();
    }
    #pragma unroll
    for (int i = 0; i < 4; ++i) {
        #pragma unroll
        for (int r = 0; r < 4; ++r) {
            int gr = row0 + wrow * 64 + i * 16 + q * 4 + r;
            if (gr < N_NODES) {
                #pragma unroll
                for (int j = 0; j < 4; ++j) {
                    int gc = col0 + wcol * 64 + j * 16 + l15;
                    C[(size_t)gr * HD + gc] = f2bf(acc[i][j][r]);
                }
            }
        }
    }
}

// ---------- pool partial (proven) ----------
__device__ __forceinline__ void pool_part(const ushort* __restrict__ h,
                                          float* __restrict__ pmax,
                                          float* __restrict__ psum,
                                          int pb, char* smem) {
    float* lmx = (float*)smem;           // 2048 floats
    float* lsm = lmx + 2048;             // 2048 floats
    const int tid = threadIdx.x;
    const int wave = tid >> 6, lane = tid & 63;
    const uint4* h4 = (const uint4*)h;
    float m[8] = {}, sm[8] = {};
    for (int r = pb * 4 + wave; r < N_NODES; r += 1024) {
        uint4 v = h4[(size_t)r * 64 + lane];
        m[0] = fmaxf(m[0], bflo(v.x)); sm[0] += bflo(v.x);
        m[1] = fmaxf(m[1], bfhi(v.x)); sm[1] += bfhi(v.x);
        m[2] = fmaxf(m[2], bflo(v.y)); sm[2] += bflo(v.y);
        m[3] = fmaxf(m[3], bfhi(v.y)); sm[3] += bfhi(v.y);
        m[4] = fmaxf(m[4], bflo(v.z)); sm[4] += bflo(v.z);
        m[5] = fmaxf(m[5], bfhi(v.z)); sm[5] += bfhi(v.z);
        m[6] = fmaxf(m[6], bflo(v.w)); sm[6] += bflo(v.w);
        m[7] = fmaxf(m[7], bfhi(v.w)); sm[7] += bfhi(v.w);
    }
    #pragma unroll
    for (int i = 0; i < 8; ++i) {
        lmx[wave * 512 + lane * 8 + i] = m[i];
        lsm[wave * 512 + lane * 8 + i] = sm[i];
    }
    __syncthreads();
    #pragma unroll
    for (int cc = 0; cc < 2; ++cc) {
        int ch = tid * 2 + cc;
        float mx = fmaxf(fmaxf(lmx[ch], lmx[512 + ch]),
                         fmaxf(lmx[1024 + ch], lmx[1536 + ch]));
        float sv = (lsm[ch] + lsm[512 + ch]) + (lsm[1024 + ch] + lsm[1536 + ch]);
        atomicMax((int*)&pmax[ch], __float_as_int(mx));   // values >= 0
        atomicAdd(&psum[ch], sv);
    }
}

// ---------- prep: cvt x | wt transpose | zero deg/pmax/psum ----------
#define NB_CVT 5000
#define NB_WT  192
#define NB_ZD  79
__global__ __launch_bounds__(256) void prep_k(const float* __restrict__ x,
                                              ushort* __restrict__ xb,
                                              const float* __restrict__ W1,
                                              const float* __restrict__ W2,
                                              const float* __restrict__ W3,
                                              ushort* __restrict__ T1,
                                              ushort* __restrict__ T2,
                                              ushort* __restrict__ T3,
                                              int* __restrict__ deg,
                                              float* __restrict__ pmax,
                                              float* __restrict__ psum) {
    __shared__ float t[64][65];
    const int b = blockIdx.x;
    const int tid = threadIdx.x;
    if (b < NB_CVT) {
        int c = b * 256 + tid;
        const float4* p = (const float4*)x + (size_t)c * 2;
        float4 a = p[0], q = p[1];
        uint4 o;
        o.x = pack2(a.x, a.y); o.y = pack2(a.z, a.w);
        o.z = pack2(q.x, q.y); o.w = pack2(q.z, q.w);
        ((uint4*)xb)[c] = o;
    } else if (b < NB_CVT + NB_WT) {
        int idx = b - NB_CVT;
        int layer = idx >> 6, rem = idx & 63;
        const float* W = (layer == 0) ? W1 : (layer == 1) ? W2 : W3;
        ushort* T      = (layer == 0) ? T1 : (layer == 1) ? T2 : T3;
        int kb = (rem >> 3) * 64, nb = (rem & 7) * 64;
        int c = tid & 63, r4 = tid >> 6;
        #pragma unroll
        for (int l = 0; l < 16; ++l) {
            int r = l * 4 + r4;
            t[r][c] = W[(size_t)(kb + r) * HD + nb + c];
        }
        __syncthreads();
        #pragma unroll
        for (int l = 0; l < 16; ++l) {
            int r = l * 4 + r4;
            T[(size_t)(nb + r) * HD + kb + c] = f2bf(t[c][r]);
        }
    } else if (b < NB_CVT + NB_WT + NB_ZD) {
        int i = (b - NB_CVT - NB_WT) * 256 + tid;
        if (i < N_NODES) deg[i] = 0;
    } else if (b < NB_CVT + NB_WT + NB_ZD + 6) {
        int i = (b - NB_CVT - NB_WT - NB_ZD) * 256 + tid;
        pmax[i] = 0.f;
    } else {
        int i = (b - NB_CVT - NB_WT - NB_ZD - 6) * 256 + tid;
        psum[i] = 0.f;
    }
}

// ---------- fused1: gemm layer1 (0..627) || hist (628..1877) ----------
__global__ __launch_bounds__(256) void fused1_k(const ushort* __restrict__ xb,
                                                const ushort* __restrict__ wt1,
                                                ushort* __restrict__ s,
                                                const int* __restrict__ rows,
                                                int* __restrict__ deg) {
    __shared__ __align__(16) char smem[16384];
    const int b = blockIdx.x;
    if (b < 628) {
        gemm_tile(xb, wt1, s, b, smem);
    } else {
        int e = (b - 628) * 256 + threadIdx.x;   // 1250*256 == N_EDGES exactly
        atomicAdd(&deg[rows[e]], 1);
    }
}

// ---------- scan: one workgroup, 16 waves, shuffle (proven ~4 µs) ----------
__global__ __launch_bounds__(1024) void scan_k(const int* __restrict__ deg,
                                               int* __restrict__ rowstart,
                                               int* __restrict__ cursor) {
    __shared__ int wsum[16];
    const int tid = threadIdx.x;
    const int lane = tid & 63, wv = tid >> 6;
    int carry = 0;
    for (int base = 0; base < N_NODES; base += 1024) {
        int i = base + tid;
        int v = (i < N_NODES) ? deg[i] : 0;
        int incl = v;
        #pragma unroll
        for (int off = 1; off < 64; off <<= 1) {
            int t = __shfl_up(incl, off, 64);
            if (lane >= off) incl += t;
        }
        if (lane == 63) wsum[wv] = incl;
        __syncthreads();
        int woff = 0, tot = 0;
        #pragma unroll
        for (int w = 0; w < 16; ++w) {
            int sv = wsum[w];
            if (w < wv) woff += sv;
            tot += sv;
        }
        if (i < N_NODES) {
            int ex = carry + woff + incl - v;
            rowstart[i] = ex;
            cursor[i]   = ex;
        }
        carry += tot;
        __syncthreads();
    }
    if (tid == 0) rowstart[N_NODES] = carry;
}

// ---------- fill CSR ----------
__global__ void fill_k(const int* __restrict__ rows, const int* __restrict__ cols,
                       const float* __restrict__ vals, int* __restrict__ cursor,
                       int* __restrict__ csr_col, float* __restrict__ csr_val) {
    int e = blockIdx.x * blockDim.x + threadIdx.x;
    if (e < N_EDGES) {
        int p = atomicAdd(&cursor[rows[e]], 1);
        csr_col[p] = cols[e];
        csr_val[p] = vals[e];
    }
}

// ---------- aggregate: one wave per row, wave-uniform metadata, unroll 8 ----
__device__ inline void fma8(float* acc, uint4 v, float w) {
    acc[0] += w * bflo(v.x); acc[1] += w * bfhi(v.x);
    acc[2] += w * bflo(v.y); acc[3] += w * bfhi(v.y);
    acc[4] += w * bflo(v.z); acc[5] += w * bfhi(v.z);
    acc[6] += w * bflo(v.w); acc[7] += w * bfhi(v.w);
}

__global__ __launch_bounds__(256) void agg_k(const ushort* __restrict__ s,
                                             const int* __restrict__ rowstart,
                                             const int* __restrict__ csr_col,
                                             const float* __restrict__ csr_val,
                                             const float* __restrict__ bias,
                                             ushort* __restrict__ hout) {
    const int wave = threadIdx.x >> 6, lane = threadIdx.x & 63;
    const int r = blockIdx.x * 4 + wave;
    const uint4* s4 = (const uint4*)s;
    float acc[8] = {};
    const int beg = rowstart[r], end = rowstart[r + 1];
    int j = beg;
    for (; j + 8 <= end; j += 8) {     // 8 independent 16B gathers in flight
        int   c0 = csr_col[j],     c1 = csr_col[j + 1];
        int   c2 = csr_col[j + 2], c3 = csr_col[j + 3];
        int   c4 = csr_col[j + 4], c5 = csr_col[j + 5];
        int   c6 = csr_col[j + 6], c7 = csr_col[j + 7];
        float w0 = csr_val[j],     w1 = csr_val[j + 1];
        float w2 = csr_val[j + 2], w3 = csr_val[j + 3];
        float w4 = csr_val[j + 4], w5 = csr_val[j + 5];
        float w6 = csr_val[j + 6], w7 = csr_val[j + 7];
        uint4 v0 = s4[(size_t)c0 * 64 + lane];
        uint4 v1 = s4[(size_t)c1 * 64 + lane];
        uint4 v2 = s4[(size_t)c2 * 64 + lane];
        uint4 v3 = s4[(size_t)c3 * 64 + lane];
        uint4 v4 = s4[(size_t)c4 * 64 + lane];
        uint4 v5 = s4[(size_t)c5 * 64 + lane];
        uint4 v6 = s4[(size_t)c6 * 64 + lane];
        uint4 v7 = s4[(size_t)c7 * 64 + lane];
        fma8(acc, v0, w0);
        fma8(acc, v1, w1);
        fma8(acc, v2, w2);
        fma8(acc, v3, w3);
        fma8(acc, v4, w4);
        fma8(acc, v5, w5);
        fma8(acc, v6, w6);
        fma8(acc, v7, w7);
    }
    for (; j + 2 <= end; j += 2) {
        int   c0 = csr_col[j],   c1 = csr_col[j + 1];
        float w0 = csr_val[j],   w1 = csr_val[j + 1];
        uint4 v0 = s4[(size_t)c0 * 64 + lane];
        uint4 v1 = s4[(size_t)c1 * 64 + lane];
        fma8(acc, v0, w0);
        fma8(acc, v1, w1);
    }
    if (j < end) {
        int   c0 = csr_col[j];
        float w0 = csr_val[j];
        uint4 v0 = s4[(size_t)c0 * 64 + lane];
        fma8(acc, v0, w0);
    }
    float4 b0 = ((const float4*)bias)[lane * 2];
    float4 b1 = ((const float4*)bias)[lane * 2 + 1];
    float o[8];
    o[0] = fmaxf(acc[0] + b0.x, 0.f); o[1] = fmaxf(acc[1] + b0.y, 0.f);
    o[2] = fmaxf(acc[2] + b0.z, 0.f); o[3] = fmaxf(acc[3] + b0.w, 0.f);
    o[4] = fmaxf(acc[4] + b1.x, 0.f); o[5] = fmaxf(acc[5] + b1.y, 0.f);
    o[6] = fmaxf(acc[6] + b1.z, 0.f); o[7] = fmaxf(acc[7] + b1.w, 0.f);
    uint4 ov;
    ov.x = pack2(o[0], o[1]); ov.y = pack2(o[2], o[3]);
    ov.z = pack2(o[4], o[5]); ov.w = pack2(o[6], o[7]);
    ((uint4*)hout)[(size_t)r * 64 + lane] = ov;
}

// ---------- fused gemm || pool (both read-only on h; proven) ----------
__global__ __launch_bounds__(256) void fusedgp_k(const ushort* __restrict__ h,
                                                 const ushort* __restrict__ wt,
                                                 ushort* __restrict__ s,
                                                 float* __restrict__ pmax,
                                                 float* __restrict__ psum) {
    __shared__ __align__(16) char smem[16384];
    const int b = blockIdx.x;
    if (b < 628) gemm_tile(h, wt, s, b, smem);
    else         pool_part(h, pmax, psum, b - 628, smem);
}

// ---------- standalone pool (layer 3) ----------
__global__ __launch_bounds__(256) void pool_k(const ushort* __restrict__ h,
                                              float* __restrict__ pmax,
                                              float* __restrict__ psum) {
    __shared__ __align__(16) char smem[16384];
    pool_part(h, pmax, psum, blockIdx.x, smem);
}

// ---------- head MLP + log_softmax (1024 threads, split-k; proven) ----------
__global__ __launch_bounds__(1024) void mlp_k(const float* __restrict__ pool_max,
                                              const float* __restrict__ pool_sum,
                                              const float* __restrict__ l1W,
                                              const float* __restrict__ l1b,
                                              const float* __restrict__ l2W,
                                              const float* __restrict__ l2b,
                                              const float* __restrict__ l3W,
                                              const float* __restrict__ l3b,
                                              float* __restrict__ out) {
    __shared__ float g[1024];
    __shared__ float part[1024];
    __shared__ float a1[128];
    __shared__ float a2[64];
    __shared__ float a3[10];
    const int tid = threadIdx.x;
    if (tid < 512) {
        g[tid]       = pool_max[tid] + pool_max[512 + tid] + pool_max[1024 + tid];
        g[512 + tid] = (pool_sum[tid] + pool_sum[512 + tid] + pool_sum[1024 + tid]) *
                       (1.0f / N_NODES);
    }
    __syncthreads();
    {
        int ch = tid & 127, sl = tid >> 7;
        float acc = (sl == 0) ? l1b[ch] : 0.f;
        int k0 = sl * 128;
        #pragma unroll 4
        for (int k = k0; k < k0 + 128; ++k) acc += g[k] * l1W[k * 128 + ch];
        part[tid] = acc;
    }
    __syncthreads();
    if (tid < 128) {
        float a = part[tid];
        #pragma unroll
        for (int ss = 1; ss < 8; ++ss) a += part[tid + ss * 128];
        a1[tid] = fmaxf(a, 0.f);
    }
    __syncthreads();
    if (tid < 512) {
        int ch = tid & 63, sl = tid >> 6;
        float acc = (sl == 0) ? l2b[ch] : 0.f;
        int k0 = sl * 16;
        #pragma unroll
        for (int k = k0; k < k0 + 16; ++k) acc += a1[k] * l2W[k * 64 + ch];
        part[tid] = acc;
    }
    __syncthreads();
    if (tid < 64) {
        float a = part[tid];
        #pragma unroll
        for (int ss = 1; ss < 8; ++ss) a += part[tid + ss * 64];
        a2[tid] = fmaxf(a, 0.f);
    }
    __syncthreads();
    if (tid < 10) {
        float acc = l3b[tid];
        for (int k = 0; k < 64; ++k) acc += a2[k] * l3W[k * 10 + tid];
        a3[tid] = acc;
    }
    __syncthreads();
    if (tid == 0) {
        float m = a3[0];
        for (int j = 1; j < 10; ++j) m = fmaxf(m, a3[j]);
        float ssum = 0.f;
        for (int j = 0; j < 10; ++j) ssum += expf(a3[j] - m);
        float lse = m + logf(ssum);
        for (int j = 0; j < 10; ++j) out[j] = a3[j] - lse;
    }
}

extern "C" void kernel_launch(void* const* d_in, const int* in_sizes, int n_in,
                              void* d_out, int out_size, void* d_ws, size_t ws_size,
                              hipStream_t stream) {
    const float* x    = (const float*)d_in[0];
    const int*   rows = (const int*)  d_in[1];
    const int*   cols = (const int*)  d_in[2];
    const float* vals = (const float*)d_in[3];
    const float* W1   = (const float*)d_in[4];
    const float* b1   = (const float*)d_in[5];
    const float* W2   = (const float*)d_in[6];
    const float* b2   = (const float*)d_in[7];
    const float* W3   = (const float*)d_in[8];
    const float* b3   = (const float*)d_in[9];
    const float* l1W  = (const float*)d_in[10];
    const float* l1b  = (const float*)d_in[11];
    const float* l2W  = (const float*)d_in[12];
    const float* l2b  = (const float*)d_in[13];
    const float* l3W  = (const float*)d_in[14];
    const float* l3b  = (const float*)d_in[15];
    float* out = (float*)d_out;

    char* ws = (char*)d_ws;
    size_t off = 0;
    auto alloc = [&](size_t bytes) {
        void* p = ws + off;
        off += (bytes + 255) & ~(size_t)255;
        return p;
    };
    ushort* xb       = (ushort*)alloc((size_t)N_NODES * HD * 2);
    ushort* s        = (ushort*)alloc((size_t)N_NODES * HD * 2);
    ushort* hb       = (ushort*)alloc((size_t)N_NODES * HD * 2);
    ushort* wt1      = (ushort*)alloc((size_t)HD * HD * 2);
    ushort* wt2      = (ushort*)alloc((size_t)HD * HD * 2);
    ushort* wt3      = (ushort*)alloc((size_t)HD * HD * 2);
    int*    deg      = (int*)   alloc((size_t)N_NODES * 4);
    float*  pmax     = (float*) alloc((size_t)3 * 512 * 4);
    float*  psum     = (float*) alloc((size_t)3 * 512 * 4);
    int*    rowstart = (int*)   alloc((size_t)(N_NODES + 1) * 4);
    int*    cursor   = (int*)   alloc((size_t)N_NODES * 4);
    int*    csr_col  = (int*)   alloc((size_t)N_EDGES * 4);
    float*  csr_val  = (float*) alloc((size_t)N_EDGES * 4);
    (void)ws_size; (void)in_sizes; (void)n_in; (void)out_size;

    // 1: prep (cvt + wt + zero deg/pmax/psum)
    prep_k<<<NB_CVT + NB_WT + NB_ZD + 12, 256, 0, stream>>>(
        x, xb, W1, W2, W3, wt1, wt2, wt3, deg, pmax, psum);
    // 2: gemm1 || hist
    fused1_k<<<628 + 1250, 256, 0, stream>>>(xb, wt1, s, rows, deg);
    // 3: scan
    scan_k<<<1, 1024, 0, stream>>>(deg, rowstart, cursor);
    // 4: fill CSR
    fill_k<<<(N_EDGES + 255) / 256, 256, 0, stream>>>(rows, cols, vals, cursor,
                                                      csr_col, csr_val);
    const int AB = N_NODES / 4;
    // 5: agg1
    agg_k<<<AB, 256, 0, stream>>>(s, rowstart, csr_col, csr_val, b1, hb);
    // 6: gemm2 || pool1
    fusedgp_k<<<628 + 256, 256, 0, stream>>>(hb, wt2, s, pmax, psum);
    // 7: agg2
    agg_k<<<AB, 256, 0, stream>>>(s, rowstart, csr_col, csr_val, b2, hb);
    // 8: gemm3 || pool2
    fusedgp_k<<<628 + 256, 256, 0, stream>>>(hb, wt3, s, pmax + 512, psum + 512);
    // 9: agg3
    agg_k<<<AB, 256, 0, stream>>>(s, rowstart, csr_col, csr_val, b3, hb);
    // 10: pool3
    pool_k<<<256, 256, 0, stream>>>(hb, pmax + 1024, psum + 1024);
    // 11: mlp head
    mlp_k<<<1, 1024, 0, stream>>>(pmax, psum, l1W, l1b, l2W, l2b, l3W, l3b, out);
}